// Round 12
// baseline (120.707 us; speedup 1.0000x reference)
//
#include <hip/hip_runtime.h>
#include <hip/hip_bf16.h>
#include <math.h>

// Problem dims (fixed by reference)
#define B   32
#define P   196      // hw tokens (14x14)
#define C   768
#define NC  4096
#define HH  14
#define KSPLIT 24    // 768 / 32
#define NT  12       // K tiles per GEMM (768 / 64)
#define M6  6272     // B*P
// Packed sub-slice layout: [kb(24)][rg(rows/64)][s(4)][r(64)][e(8)]
//   element (row, k) at kb=k>>5, rg=row>>6, s=(k>>3)&3, r=row&63, e=k&7.
//   One (kb,rg) chunk = 2048 f16 = 4 KB contiguous; LDS fragment reads are
//   16 B row stride -> conflict-free.
#define TOK_KB 200704        // 98 * 2048 elements
#define WT_KB  24576         // 12 * 2048 elements

typedef _Float16 half8 __attribute__((ext_vector_type(8)));
typedef _Float16 half4 __attribute__((ext_vector_type(4)));
typedef float f32x4 __attribute__((ext_vector_type(4)));

#define GLOAD_LDS16(g, l)                                                      \
    __builtin_amdgcn_global_load_lds(                                          \
        (const __attribute__((address_space(1))) void*)(g),                    \
        (__attribute__((address_space(3))) void*)(l), 16, 0, 0)

// ---------------------------------------------------------------------------
// K1: SpaceSelfAware + space_fusion + residual.
// 16-channel blocks, grid (48, 32) = 1536 (~6/CU, 19 KB LDS) for TLP.
// Zero-padded 16x16 spatial halo tile; branchless 9-tap window.
// Thread (cc = tid&15, g = tid>>4): channel cc, tokens p = g, g+16, ...
// Partial reduction: shfl_xor over the wave's 4 groups, then 4 waves via LDS.
// ---------------------------------------------------------------------------
__global__ __launch_bounds__(256) void k_ssa(const float* __restrict__ t,
                                             float* __restrict__ pre) {
    const int b = blockIdx.y, c0 = blockIdx.x * 16;
    __shared__ float xp_[256 * 16];        // [(i+2)*16 + (j+1)][cc]  16 KB
    __shared__ float part[4][9][16];
    __shared__ float inv_norm[9][16];
    const int tid = threadIdx.x;
    const int cc = tid & 15, g = tid >> 4, wv = tid >> 6;

#pragma unroll
    for (int q = 0; q < 16; ++q) xp_[q * 256 + tid] = 0.0f;
    __syncthreads();

    // fill valid region: 784 float4
    for (int idx = tid; idx < 784; idx += 256) {
        const int p = idx >> 2, c = (idx & 3) * 4;
        const int i = p / HH, j = p % HH;
        *(float4*)&xp_[((i + 2) * 16 + (j + 1)) * 16 + c] =
            *(const float4*)&t[((size_t)b * P + p) * C + c0 + c];
    }
    __syncthreads();

    float s[9] = {};
    {
        int i = 0, j = g;
        if (j >= HH) { j -= HH; i = 1; }
        for (int p = g; p < P; p += 16) {
            const int base = ((i + 2) * 16 + (j + 1)) * 16 + cc;
            const float xp = xp_[base];
            const float xp2 = xp * xp;
#pragma unroll
            for (int k = 0; k < 9; ++k) {
                const int off = ((k / 3) - 2) * 16 + (k % 3) - 1;  // const
                const float nb = xp_[base + off * 16];
                s[k] += xp2 * nb * nb;
            }
            j += 2; ++i;
            if (j >= HH) { j -= HH; ++i; }
        }
    }
    // in-wave fixed-order reduce across the wave's 4 groups
#pragma unroll
    for (int k = 0; k < 9; ++k) {
        float r = s[k];
        r += __shfl_xor(r, 16);
        r += __shfl_xor(r, 32);
        s[k] = r;
    }
    if ((tid & 63) < 16) {
#pragma unroll
        for (int k = 0; k < 9; ++k) part[wv][k][cc] = s[k];
    }
    __syncthreads();
    if (tid < 144) {
        const int k = tid >> 4, c2 = tid & 15;
        const float t4 = part[0][k][c2] + part[1][k][c2] +
                         part[2][k][c2] + part[3][k][c2];
        inv_norm[k][c2] = 1.0f / fmaxf(sqrtf(t4), 1e-12f);
    }
    __syncthreads();

    float invn[9];
#pragma unroll
    for (int k = 0; k < 9; ++k) invn[k] = inv_norm[k][cc];

    {
        int i = 0, j = g;
        if (j >= HH) { j -= HH; i = 1; }
        for (int p = g; p < P; p += 16) {
            const int base = ((i + 2) * 16 + (j + 1)) * 16 + cc;
            const float xp = xp_[base];
            float acc = 0.0f;
#pragma unroll
            for (int k = 0; k < 9; ++k) {
                const int off = ((k / 3) - 2) * 16 + (k % 3) - 1;
                const float v = xp * xp_[base + off * 16];
                const float u = fmaxf(v * invn[k], 1e-6f);
                acc += u * u * u;
            }
            pre[((size_t)b * P + p) * C + c0 + cc] =
                cbrtf(acc * (1.0f / 9.0f)) + xp;
            j += 2; ++i;
            if (j >= HH) { j -= HH; ++i; }
        }
    }
}

// ---------------------------------------------------------------------------
// K2: L2 normalize each (b,p) row over 768 channels; write f16 tokens in
// PACKED sub-slice layout via an LDS bounce (96 x half8 stores).
// ---------------------------------------------------------------------------
__global__ __launch_bounds__(256) void k_rownorm(const float* __restrict__ in,
                                                 _Float16* __restrict__ outP) {
    const int row = blockIdx.x;               // b*P + p
    const float* r = in + (size_t)row * C;
    const int tid = threadIdx.x;
    float vals[3];
    float s = 0.0f;
#pragma unroll
    for (int q = 0; q < 3; ++q) {
        vals[q] = r[tid + q * 256];
        s += vals[q] * vals[q];
    }
    __shared__ float partial[4];
    __shared__ float inv;
    __shared__ _Float16 nrm[C];
#pragma unroll
    for (int off = 32; off > 0; off >>= 1) s += __shfl_xor(s, off);
    if ((tid & 63) == 0) partial[tid >> 6] = s;
    __syncthreads();
    if (tid == 0)
        inv = 1.0f / fmaxf(sqrtf(partial[0] + partial[1] + partial[2] + partial[3]), 1e-12f);
    __syncthreads();
#pragma unroll
    for (int q = 0; q < 3; ++q)
        nrm[tid + q * 256] = (_Float16)(vals[q] * inv);
    __syncthreads();
    if (tid < 96) {
        const half8 v = *(const half8*)&nrm[tid * 8];
        const int kb = tid >> 2, s8 = tid & 3;   // c = tid*8
        const int rg = row >> 6, rr = row & 63;
        *(half8*)&outP[(size_t)kb * TOK_KB + rg * 2048 + s8 * 512 + rr * 8] = v;
    }
}

// ---------------------------------------------------------------------------
// K2b: weight pack: W (K x N) f32 -> WtP packed [kb][rg][s][r][8] f16
// ---------------------------------------------------------------------------
__global__ __launch_bounds__(256) void k_wt(const float* __restrict__ W,
                                            _Float16* __restrict__ WtP) {
    __shared__ float tt[32][33];
    const int k0 = blockIdx.x * 32, n0 = blockIdx.y * 32;   // kb = blockIdx.x
    const int r = threadIdx.x / 32, c = threadIdx.x % 32;
#pragma unroll
    for (int q = 0; q < 4; ++q)
        tt[r + q * 8][c] = W[(size_t)(k0 + r + q * 8) * C + n0 + c];
    __syncthreads();
    const int nl = threadIdx.x >> 3, h = threadIdx.x & 7;
    const int n = n0 + nl;
    const int rg = n >> 6, rr = n & 63, s8 = h >> 1, e0 = (h & 1) * 4;
    half4 v;
#pragma unroll
    for (int j = 0; j < 4; ++j) v[j] = (_Float16)tt[h * 4 + j][nl];
    *(half4*)&WtP[(size_t)blockIdx.x * WT_KB + rg * 2048 + s8 * 512 + rr * 8 + e0] = v;
}

// ---------------------------------------------------------------------------
// K3/K4: f16 MFMA GEMM, 128M x 64N tile, BK=64, 3-deep counted-vmcnt
// pipeline (R7/R11 sync structure).  Packed sub-slice operands: staging is
// contiguous 4 KB chunks (6 x 1 KB gload_lds per wave per stage, vmcnt
// steady wait = 12), and LDS fragment reads have 16 B row stride ->
// bank-conflict-free.  4 waves, wave = 32m x 64n = 16 MFMA per K-step
// (2x R11 MFMA per barrier pair).  Grid 588 1-D, XCD swizzle keeps the
// 12 n-tiles of one m-row on one XCD.  LDS 72 KB -> 2 blocks/CU.
// GELU=true: output packed f16.  GELU=false: f32 row-major.
// ---------------------------------------------------------------------------
template <bool GELU>
__global__ __launch_bounds__(256) void k_mfma_gemm(
    const _Float16* __restrict__ TokP,  // packed [24][98][4][64][8]  B-op
    const _Float16* __restrict__ WtP,   // packed [24][12][4][64][8]  A-op
    const float* __restrict__ bias,     // (N)
    void* __restrict__ Cout) {          // packed f16 (GELU) or f32 row-major
    __shared__ _Float16 lA[3][2][2048];     // [buf][kbL][s*512 + r*8 + e]
    __shared__ _Float16 lB[3][2][2][2048];  // [buf][kbL][rgHalf][...]
    const int tid = threadIdx.x;
    const int w = tid >> 6, l = tid & 63;
    const int l15 = l & 15, lk = l >> 4;

    // XCD swizzle: equal lid%8 (one XCD) covers one m-row's 12 n-tiles.
    const int lid = blockIdx.x;
    int vm, vn;
    if (lid < 576) { vm = (lid / 96) * 8 + (lid & 7); vn = (lid % 96) >> 3; }
    else           { vm = 48; vn = lid - 576; }
    const int m0 = vm * 128, n0 = vn * 64;
    const int wm = w * 32;
    const int rgHalf = w >> 1;

    f32x4 acc[4][2] = {};   // [fa over n][fb over m]

    // staging: 24 x 1KB loads/stage; wave w takes gc = w*6 + q, q=0..5.
#define ISSUE(tt_, bf_)                                                        \
    {                                                                          \
        _Pragma("unroll")                                                      \
        for (int q = 0; q < 6; ++q) {                                          \
            const int gc = w * 6 + q, cid = gc >> 2, ld = gc & 3;              \
            const bool isA = cid < 2;                                          \
            const int kbp = isA ? cid : ((cid - 2) >> 1);                      \
            const int rgs = isA ? 0 : ((cid - 2) & 1);                         \
            const _Float16* s_ = isA                                           \
                ? WtP + (size_t)(2 * (tt_) + kbp) * WT_KB + vn * 2048          \
                : TokP + (size_t)(2 * (tt_) + kbp) * TOK_KB +                  \
                      (2 * vm + rgs) * 2048;                                   \
            _Float16* d_ = isA ? &lA[bf_][kbp][0] : &lB[bf_][kbp][rgs][0];     \
            GLOAD_LDS16(s_ + ld * 512 + l * 8, d_ + ld * 512 + l * 8);         \
        }                                                                      \
    }

    ISSUE(0, 0); ISSUE(1, 1); ISSUE(2, 2);   // 18 loads in flight / wave

    for (int t = 0; t < NT; ++t) {
        if (t < NT - 2)       asm volatile("s_waitcnt vmcnt(12)" ::: "memory");
        else if (t == NT - 2) asm volatile("s_waitcnt vmcnt(6)" ::: "memory");
        else                  asm volatile("s_waitcnt vmcnt(0)" ::: "memory");
        __builtin_amdgcn_s_barrier();          // all waves' tile-t loads done
        __builtin_amdgcn_sched_barrier(0);

        const int buf = t % 3;
#pragma unroll
        for (int kk = 0; kk < 2; ++kk) {
            half8 af[4], bf2[2];
#pragma unroll
            for (int fa = 0; fa < 4; ++fa)
                af[fa] = *(const half8*)&lA[buf][kk][lk * 512 + (fa * 16 + l15) * 8];
#pragma unroll
            for (int fb = 0; fb < 2; ++fb) {
                const int mr = (wm + fb * 16 + l15) & 63;
                bf2[fb] = *(const half8*)&lB[buf][kk][rgHalf][lk * 512 + mr * 8];
            }
#pragma unroll
            for (int fa = 0; fa < 4; ++fa)
#pragma unroll
                for (int fb = 0; fb < 2; ++fb)
                    acc[fa][fb] = __builtin_amdgcn_mfma_f32_16x16x32_f16(
                        af[fa], bf2[fb], acc[fa][fb], 0, 0, 0);
        }
        asm volatile("s_waitcnt lgkmcnt(0)" ::: "memory");  // reads retired
        __builtin_amdgcn_s_barrier();          // safe to overwrite buf
        __builtin_amdgcn_sched_barrier(0);
        if (t < NT - 3) ISSUE(t + 3, buf);     // refill; stays in flight
    }
#undef ISSUE

    // epilogue: lane holds D[n = nb + r][m], r=0..3 consecutive n
#pragma unroll
    for (int fa = 0; fa < 4; ++fa) {
        const int nb = n0 + fa * 16 + lk * 4;
        const float4 bv = *(const float4*)&bias[nb];
#pragma unroll
        for (int fb = 0; fb < 2; ++fb) {
            const int m = m0 + wm + fb * 16 + l15;
            if (GELU) {
                half4 o;
#pragma unroll
                for (int rr = 0; rr < 4; ++rr) {
                    float v = acc[fa][fb][rr] + ((const float*)&bv)[rr];
                    v = 0.5f * v * (1.0f + erff(v * 0.70710678118654752f));
                    o[rr] = (_Float16)v;
                }
                const int kb = nb >> 5, s8 = (nb >> 3) & 3, e0 = nb & 7;
                *(half4*)&((_Float16*)Cout)[(size_t)kb * TOK_KB +
                                            (m >> 6) * 2048 + s8 * 512 +
                                            (m & 63) * 8 + e0] = o;
            } else {
                float4 o;
#pragma unroll
                for (int rr = 0; rr < 4; ++rr)
                    ((float*)&o)[rr] = acc[fa][fb][rr] + ((const float*)&bv)[rr];
                *(float4*)&((float*)Cout)[(size_t)m * C + nb] = o;
            }
        }
    }
}

// ---------------------------------------------------------------------------
// K5: GeM over tokens: g[b,c] = (mean_p clip(x,1e-6)^3)^(1/3)
// ---------------------------------------------------------------------------
__global__ __launch_bounds__(256) void k_gempool(const float* __restrict__ tk,
                                                 float* __restrict__ g) {
    const int b = blockIdx.x / 3;
    const int c = (blockIdx.x % 3) * 256 + threadIdx.x;
    float s = 0.0f;
#pragma unroll 4
    for (int p = 0; p < P; ++p) {
        const float v = fmaxf(tk[((size_t)b * P + p) * C + c], 1e-6f);
        s += v * v * v;
    }
    g[b * C + c] = cbrtf(s * (1.0f / (float)P));
}

// ---------------------------------------------------------------------------
// K6a: head GEMM stage 1 (split-K).  grid (NC/64, KSPLIT) = 1536 blocks.
// ---------------------------------------------------------------------------
__global__ __launch_bounds__(256) void k_head1(const float* __restrict__ g,
                                               const float* __restrict__ W,
                                               float* __restrict__ partial) {
    const int n0 = blockIdx.x * 64;
    const int k0 = blockIdx.y * 32;
    __shared__ float gs[32][32];          // [b][kk]
    __shared__ float part[4][32][64];     // [q][b][c]
    const int tid = threadIdx.x;

    for (int idx = tid; idx < 32 * 32; idx += 256)
        gs[idx >> 5][idx & 31] = g[(idx >> 5) * C + k0 + (idx & 31)];
    __syncthreads();

    const int c = tid & 63, q = tid >> 6;
    float acc[32] = {};
#pragma unroll
    for (int kk = 0; kk < 8; ++kk) {
        const int k = q * 8 + kk;
        const float wv = W[(size_t)(k0 + k) * NC + n0 + c];
#pragma unroll
        for (int b = 0; b < 32; ++b) acc[b] += gs[b][k] * wv;
    }
#pragma unroll
    for (int b = 0; b < 32; ++b) part[q][b][c] = acc[b];
    __syncthreads();

    for (int o = tid; o < 32 * 64; o += 256) {
        const int b = o >> 6, cc = o & 63;
        const float v = part[0][b][cc] + part[1][b][cc] +
                        part[2][b][cc] + part[3][b][cc];
        partial[((size_t)blockIdx.y * 32 + b) * NC + n0 + cc] = v;
    }
}

// ---------------------------------------------------------------------------
// K6b: head GEMM stage 2: fixed-order sum of KSPLIT partials + bias.
// ---------------------------------------------------------------------------
__global__ __launch_bounds__(256) void k_head2(const float* __restrict__ partial,
                                               const float* __restrict__ hb,
                                               float* __restrict__ out) {
    const int n = blockIdx.x * 256 + threadIdx.x;
    const int b = blockIdx.y;
    float s = hb[n];
#pragma unroll
    for (int ks = 0; ks < KSPLIT; ++ks)
        s += partial[((size_t)ks * 32 + b) * NC + n];
    out[(size_t)b * NC + n] = s;
}

// ---------------------------------------------------------------------------
// K7: L2-normalize each batch row of out (4096) in place.
// ---------------------------------------------------------------------------
__global__ __launch_bounds__(256) void k_outnorm(float* __restrict__ out) {
    const int b = blockIdx.x;
    float* r = out + (size_t)b * NC;
    const int tid = threadIdx.x;
    float v[16];
    float s = 0.0f;
#pragma unroll
    for (int q = 0; q < 16; ++q) {
        v[q] = r[tid + q * 256];
        s += v[q] * v[q];
    }
    __shared__ float partial[4];
    __shared__ float inv;
#pragma unroll
    for (int off = 32; off > 0; off >>= 1) s += __shfl_xor(s, off);
    if ((tid & 63) == 0) partial[tid >> 6] = s;
    __syncthreads();
    if (tid == 0)
        inv = 1.0f / fmaxf(sqrtf(partial[0] + partial[1] + partial[2] + partial[3]), 1e-12f);
    __syncthreads();
#pragma unroll
    for (int q = 0; q < 16; ++q) r[tid + q * 256] = v[q] * inv;
}

// ---------------------------------------------------------------------------
extern "C" void kernel_launch(void* const* d_in, const int* in_sizes, int n_in,
                              void* d_out, int out_size, void* d_ws, size_t ws_size,
                              hipStream_t stream) {
    const float* patch  = (const float*)d_in[0];
    const float* fc1_w  = (const float*)d_in[1];
    const float* fc1_b  = (const float*)d_in[2];
    const float* fc2_w  = (const float*)d_in[3];
    const float* fc2_b  = (const float*)d_in[4];
    const float* head_w = (const float*)d_in[5];
    const float* head_b = (const float*)d_in[6];
    float* out = (float*)d_out;

    const size_t big = (size_t)B * P * C;        // 4,816,896 elements
    float*    pre  = (float*)d_ws;               // [big] f32; later reused as tok2
    _Float16* tokP = (_Float16*)(pre + big);     // [big] f16 packed
    _Float16* hdnP = tokP + big;                 // [big] f16 packed
    _Float16* wt1  = hdnP + big;                 // [768*768] f16 packed
    _Float16* wt2  = wt1 + C * C;                // [768*768] f16 packed
    float*    gbuf = (float*)(wt2 + C * C);      // [32*768] f32
    float*    hpart = gbuf + B * C;              // [KSPLIT*32*4096] f32
    float*    tok2 = pre;                        // reuse

    // K1: SSA + fusion + residual -> pre
    k_ssa<<<dim3(C / 16, B), dim3(256), 0, stream>>>(patch, pre);
    // weight packs (independent)
    k_wt<<<dim3(C / 32, C / 32), dim3(256), 0, stream>>>(fc1_w, wt1);
    k_wt<<<dim3(C / 32, C / 32), dim3(256), 0, stream>>>(fc2_w, wt2);
    // K2: channel L2 norm -> tokP (f16 packed)
    k_rownorm<<<dim3(B * P), dim3(256), 0, stream>>>(pre, tokP);
    // K3: fc1 + gelu -> hdnP (f16 packed)
    k_mfma_gemm<true><<<dim3(588), dim3(256), 0, stream>>>(
        tokP, wt1, fc1_b, hdnP);
    // K4: fc2 -> tok2 (f32 row-major)
    k_mfma_gemm<false><<<dim3(588), dim3(256), 0, stream>>>(
        hdnP, wt2, fc2_b, tok2);
    // K5: GeM over tokens -> gbuf
    k_gempool<<<dim3(B * 3), dim3(256), 0, stream>>>(tok2, gbuf);
    // K6: head GEMM, split-K two-stage -> out (pre-normalized)
    k_head1<<<dim3(NC / 64, KSPLIT), dim3(256), 0, stream>>>(gbuf, head_w, hpart);
    k_head2<<<dim3(NC / 256, B), dim3(256), 0, stream>>>(hpart, head_b, out);
    // K7: normalize rows of out
    k_outnorm<<<dim3(B), dim3(256), 0, stream>>>(out);
}